// Round 9
// baseline (365.374 us; speedup 1.0000x reference)
//
#include <hip/hip_runtime.h>
#include <stdint.h>

typedef short s16x8 __attribute__((ext_vector_type(8)));
typedef float f32x4 __attribute__((ext_vector_type(4)));
typedef uint32_t u32x4 __attribute__((ext_vector_type(4)));

#define MFMA16(a, b, c) __builtin_amdgcn_mfma_f32_16x16x32_bf16(a, b, c, 0, 0, 0)
#define NBLK 512

__device__ __forceinline__ short f2bf(float f) {
  uint32_t u = __builtin_bit_cast(uint32_t, f);
  u += 0x7FFFu + ((u >> 16) & 1u);   // round-to-nearest-even
  return (short)(u >> 16);
}
// 1-op f32->bf16 via HW packed convert (RNE). Low 16 bits = cvt(lo).
__device__ __forceinline__ uint32_t cvtpk(float lo, float hi) {
  uint32_t r;
  asm("v_cvt_pk_bf16_f32 %0, %1, %2" : "=v"(r) : "v"(lo), "v"(hi));
  return r;
}
__device__ __forceinline__ short f2bf1(float f) { return (short)cvtpk(f, f); }

// ---------------------------------------------------------------------------
// Weight pre-pack (unchanged, cold): bf16, MFMA B-fragment order.
// k = ks*32 + (lane>>4)*8 + e, n = ct*16 + (lane&15).
//   W0 frags 0..15, GB 16..111, WH 112..175, D1 176..191.  192 KiB in d_ws.
// ---------------------------------------------------------------------------
__global__ void pack_w(const float* __restrict__ w0, const float* __restrict__ wh,
                       const float* __restrict__ gw, const float* __restrict__ bw,
                       const float* __restrict__ d1, short* __restrict__ out) {
  int idx = blockIdx.x * 512 + threadIdx.x;
  if (idx >= 98304) return;
  int f = idx >> 9;
  int r = idx & 511;
  int lane = r >> 3, e = r & 7;
  int kk = ((lane >> 4) << 3) + e;
  int nn = lane & 15;
  float v;
  if (f < 16) {
    int ct = f >> 1, ks = f & 1;
    int k = ks * 32 + kk, n = ct * 16 + nn;
    if (k < 48) v = w0[(1 + k) * 128 + n];
    else if (k == 48) v = w0[n];
    else v = 0.f;
  } else if (f < 112) {
    int f2 = f - 16;
    int ks = f2 & 1, ct = (f2 >> 1) & 7, gb = (f2 >> 4) & 1, l = f2 >> 5;
    int k = ks * 32 + kk, n = ct * 16 + nn;
    const float* Wp = gb ? bw : gw;
    v = Wp[(l * 64 + k) * 128 + n];
  } else if (f < 176) {
    int f2 = f - 112;
    int ks = f2 & 3, ct = (f2 >> 2) & 7, i = f2 >> 5;
    int k = ks * 32 + kk, n = ct * 16 + nn;
    v = wh[(i * 128 + k) * 128 + n];
  } else {
    int f2 = f - 176;
    int ks = f2 & 3, ct = f2 >> 2;
    int k = ks * 32 + kk, n = ct * 16 + nn;
    v = d1[k * 64 + n];
  }
  out[idx] = f2bf(v);
}

// ---------------------------------------------------------------------------
// R9 main kernel: persistent R4 structure with CORRECTLY-PLACED prefetch.
// Key rule learned R5: __syncthreads == s_waitcnt vmcnt(0) + s_barrier, so a
// prefetch issued just BEFORE a barrier gets its full latency exposed at the
// drain.  Prefetches must issue just AFTER a barrier so the following compute
// phase covers them before the next drain:
//   issueA(t+1) (scalars+cf)  right after stage-barrier  -> covered by L0
//   issueT(t+1) (ts stream)   right after L0-barrier     -> covered by R1
// Compute structure identical to R4 (race-clean): frag-linear LDS, single
// in-place xA with read->bar->write->bar, dedicated red, f32 reg residual.
// All f32->bf16 via v_cvt_pk_bf16_f32 (1 VALU op; pairs where possible).
// ---------------------------------------------------------------------------
__global__ __launch_bounds__(512) void ngc_main(
    const float* __restrict__ coords, const float* __restrict__ angles,
    const float* __restrict__ rho, const float* __restrict__ rho_n,
    const float* __restrict__ cf, const float* __restrict__ ts,
    const float* __restrict__ gt0, const float* __restrict__ gr0,
    const float* __restrict__ gt1, const float* __restrict__ gr1,
    const float* __restrict__ gt2, const float* __restrict__ gr2,
    const float* __restrict__ f0b, const float* __restrict__ fhb,
    const float* __restrict__ gab, const float* __restrict__ beb,
    const float* __restrict__ d1b, const float* __restrict__ d2w,
    const float* __restrict__ d2b, const short* __restrict__ pw,
    float* __restrict__ out, int n, int ntiles) {
  __shared__ __align__(16) char smem[33 * 1024];
  char* featA = smem;               // 8 KiB: frag = rg*2+ks (ks<2)
  char* cfA   = smem + 8 * 1024;    // 8 KiB: frag = rg*2+ks
  char* xA    = smem + 16 * 1024;   // 16 KiB: frag = rg*4+ks (ks<4)
  float* red  = (float*)(smem + 32 * 1024);  // 1 KiB, dedicated

  const int tid = threadIdx.x;
  const int lane = tid & 63;
  const int w = tid >> 6;           // wave id == col-tile ct, 0..7
  const int g16 = lane >> 4;
  const int l15 = lane & 15;
  const int col = w * 16 + l15;
  const int cbase = col >> 5;
  const int cslot = ((col >> 3) & 3) * 16;
  const int ce = (col & 7) * 2;

  const int r_g = tid & 63;         // gather / rho row role
  const int g_id = tid >> 6;        // gather grid role (valid if <6)
  const int r_cf = tid >> 3;        // cf row role
  const int cb = tid & 7;           // cf col-block role

  // loop-carried prefetch registers
  float c_, a_, rn_, rhov;
  float4 cf0, cf1;
  float tsr[4][4];

  auto issueA = [&](int tt) {       // scalars + cf for tile tt
    int row0 = tt * 64;
    int gr1 = row0 + r_g; gr1 = gr1 < n ? gr1 : n - 1;
    c_ = coords[gr1]; a_ = angles[gr1]; rn_ = rho_n[gr1]; rhov = rho[gr1];
    int gr2 = row0 + r_cf; gr2 = gr2 < n ? gr2 : n - 1;
    const float4* cp = (const float4*)(cf + (size_t)gr2 * 64 + cb * 8);
    cf0 = cp[0]; cf1 = cp[1];
  };
  auto issueT = [&](int tt) {       // ts for tile tt
    int row0 = tt * 64;
#pragma unroll
    for (int rg = 0; rg < 4; ++rg)
#pragma unroll
      for (int rr = 0; rr < 4; ++rr) {
        int grow = row0 + rg * 16 + g16 * 4 + rr; grow = grow < n ? grow : n - 1;
        tsr[rg][rr] = ts[(size_t)grow * 128 + col];
      }
  };

  auto ldF = [&](const char* b, int frag) -> s16x8 {
    return *(const s16x8*)(b + (frag * 64 + lane) * 16);
  };
  auto ldw = [&](int frag) -> s16x8 { return ((const s16x8*)pw)[frag * 64 + lane]; };

  int t = blockIdx.x;
  issueA(t);
  issueT(t);

  for (; t < ntiles; t += NBLK) {
    const int row0 = t * 64;
    const int tn = t + NBLK;

    // ---- stage: gathers + cf + rho into LDS (consumes prefetched regs) ---
    if (tid < 384) {
      int r = r_g, g = g_id;                  // g wave-uniform
      float u = (g < 3) ? a_ : rn_;
      int lvl = (g < 3) ? g : g - 3;
      const float* G = (g == 0) ? gt0 : (g == 1) ? gt1 : (g == 2) ? gt2
                     : (g == 3) ? gr0 : (g == 4) ? gr1 : gr2;
      int Wg = 128 << lvl;
      float x = u * (float)(Wg - 1), y = c_ * (float)(Wg - 1);
      int ix = (int)x; ix = ix < 0 ? 0 : (ix > Wg - 2 ? Wg - 2 : ix);
      int iy = (int)y; iy = iy < 0 ? 0 : (iy > Wg - 2 ? Wg - 2 : iy);
      float wx = x - (float)ix, wy = y - (float)iy;
      const float4* p0 = (const float4*)(G + (size_t)(iy * Wg + ix) * 8);
      const float4* p1 = (const float4*)(G + (size_t)((iy + 1) * Wg + ix) * 8);
      float4 c00a = p0[0], c00b = p0[1], c01a = p0[2], c01b = p0[3];
      float4 c10a = p1[0], c10b = p1[1], c11a = p1[2], c11b = p1[3];
      float w00 = (1.f - wx) * (1.f - wy), w01 = wx * (1.f - wy);
      float w10 = (1.f - wx) * wy, w11 = wx * wy;
      float e0 = c00a.x * w00 + c01a.x * w01 + c10a.x * w10 + c11a.x * w11;
      float e1 = c00a.y * w00 + c01a.y * w01 + c10a.y * w10 + c11a.y * w11;
      float e2 = c00a.z * w00 + c01a.z * w01 + c10a.z * w10 + c11a.z * w11;
      float e3 = c00a.w * w00 + c01a.w * w01 + c10a.w * w10 + c11a.w * w11;
      float e4 = c00b.x * w00 + c01b.x * w01 + c10b.x * w10 + c11b.x * w11;
      float e5 = c00b.y * w00 + c01b.y * w01 + c10b.y * w10 + c11b.y * w11;
      float e6 = c00b.z * w00 + c01b.z * w01 + c10b.z * w10 + c11b.z * w11;
      float e7 = c00b.w * w00 + c01b.w * w01 + c10b.w * w10 + c11b.w * w11;
      u32x4 o = { cvtpk(e0, e1), cvtpk(e2, e3), cvtpk(e4, e5), cvtpk(e6, e7) };
      int dst16 = ((r >> 4) * 2 + (g >> 2)) * 64 + (g & 3) * 16 + (r & 15);
      *(u32x4*)(featA + dst16 * 16) = o;
    }
    {
      u32x4 s = { cvtpk(cf0.x, cf0.y), cvtpk(cf0.z, cf0.w),
                  cvtpk(cf1.x, cf1.y), cvtpk(cf1.z, cf1.w) };
      int dst16 = ((r_cf >> 4) * 2 + (cb >> 2)) * 64 + (cb & 3) * 16 + (r_cf & 15);
      *(u32x4*)(cfA + dst16 * 16) = s;
    }
    if (tid < 64) {
      int r = tid;
      s16x8 a = { f2bf1(rhov), 0, 0, 0, 0, 0, 0, 0 };
      s16x8 z = { 0, 0, 0, 0, 0, 0, 0, 0 };
      int base = ((r >> 4) * 2 + 1) * 64;
      *(s16x8*)(featA + (base + 32 + (r & 15)) * 16) = a;
      *(s16x8*)(featA + (base + 48 + (r & 15)) * 16) = z;
    }
    __syncthreads();                 // drains the gather loads (needed now)

    // ---- prefetch scalars+cf for t+1: JUST AFTER barrier, covered by L0 --
    if (tn < ntiles) issueA(tn);

    float xr[4][4];

    // ---- Layer 0: xr = silu(g0*(feat@W0+b0)+be0) + ts; xA = bf16(xr) -----
    {
      s16x8 bw0 = ldw(w * 2), bw1 = ldw(w * 2 + 1);
      s16x8 bg0 = ldw(16 + w * 2), bg1 = ldw(16 + w * 2 + 1);
      s16x8 bb0 = ldw(32 + w * 2), bb1 = ldw(32 + w * 2 + 1);
      float f0bv = f0b[col], gabv = gab[col], bebv = beb[col];
#pragma unroll
      for (int rg = 0; rg < 4; ++rg) {
        s16x8 a0 = ldF(featA, rg * 2), a1 = ldF(featA, rg * 2 + 1);
        s16x8 c0 = ldF(cfA, rg * 2), c1 = ldF(cfA, rg * 2 + 1);
        f32x4 tt = {0.f, 0.f, 0.f, 0.f};
        tt = MFMA16(a0, bw0, tt); tt = MFMA16(a1, bw1, tt);
        f32x4 ga = {0.f, 0.f, 0.f, 0.f};
        ga = MFMA16(c0, bg0, ga); ga = MFMA16(c1, bg1, ga);
        f32x4 be = {0.f, 0.f, 0.f, 0.f};
        be = MFMA16(c0, bb0, be); be = MFMA16(c1, bb1, be);
        char* xbase = xA + (rg * 4 + cbase) * 1024 + ce;
#pragma unroll
        for (int rr = 0; rr < 4; ++rr) {
          float z = (ga[rr] + gabv) * (tt[rr] + f0bv) + (be[rr] + bebv);
          float sl = z * __builtin_amdgcn_rcpf(1.f + __expf(-z));
          xr[rg][rr] = sl + tsr[rg][rr];
          *(short*)(xbase + (cslot + g16 * 4 + rr) * 16) = f2bf1(xr[rg][rr]);
        }
      }
    }
    __syncthreads();                 // drains issueA loads (covered by L0)

    // ---- prefetch ts for t+1: JUST AFTER barrier, covered by R1 read -----
    if (tn < ntiles) issueT(tn);

    // ---- Residual FiLM blocks: read xA -> bar -> write xA -> bar ---------
#pragma unroll
    for (int i = 0; i < 2; ++i) {
      s16x8 bh0 = ldw(112 + i * 32 + w * 4);
      s16x8 bh1 = ldw(112 + i * 32 + w * 4 + 1);
      s16x8 bh2 = ldw(112 + i * 32 + w * 4 + 2);
      s16x8 bh3 = ldw(112 + i * 32 + w * 4 + 3);
      s16x8 bg0 = ldw(16 + (i + 1) * 32 + w * 2);
      s16x8 bg1 = ldw(16 + (i + 1) * 32 + w * 2 + 1);
      s16x8 bb0 = ldw(16 + (i + 1) * 32 + 16 + w * 2);
      s16x8 bb1 = ldw(16 + (i + 1) * 32 + 16 + w * 2 + 1);
      float fhbv = fhb[i * 128 + col];
      float gabv = gab[(i + 1) * 128 + col];
      float bebv = beb[(i + 1) * 128 + col];
      f32x4 zs[4];
#pragma unroll
      for (int rg = 0; rg < 4; ++rg) {
        s16x8 xa = ldF(xA, rg * 4), xb = ldF(xA, rg * 4 + 1);
        s16x8 xc = ldF(xA, rg * 4 + 2), xd = ldF(xA, rg * 4 + 3);
        s16x8 c0 = ldF(cfA, rg * 2), c1 = ldF(cfA, rg * 2 + 1);
        f32x4 tt = {0.f, 0.f, 0.f, 0.f};
        tt = MFMA16(xa, bh0, tt); tt = MFMA16(xb, bh1, tt);
        tt = MFMA16(xc, bh2, tt); tt = MFMA16(xd, bh3, tt);
        f32x4 ga = {0.f, 0.f, 0.f, 0.f};
        ga = MFMA16(c0, bg0, ga); ga = MFMA16(c1, bg1, ga);
        f32x4 be = {0.f, 0.f, 0.f, 0.f};
        be = MFMA16(c0, bb0, be); be = MFMA16(c1, bb1, be);
        f32x4 z;
#pragma unroll
        for (int rr = 0; rr < 4; ++rr) {
          float zz = (ga[rr] + gabv) * (tt[rr] + fhbv) + (be[rr] + bebv);
          z[rr] = zz * __builtin_amdgcn_rcpf(1.f + __expf(-zz));
        }
        zs[rg] = z;
      }
      __syncthreads();   // all waves' MFMA reads of xA complete
#pragma unroll
      for (int rg = 0; rg < 4; ++rg) {
        char* xbase = xA + (rg * 4 + cbase) * 1024 + ce;
#pragma unroll
        for (int rr = 0; rr < 4; ++rr) {
          xr[rg][rr] += zs[rg][rr];
          *(short*)(xbase + (cslot + g16 * 4 + rr) * 16) = f2bf1(xr[rg][rr]);
        }
      }
      __syncthreads();   // in-place writes complete
    }

    // ---- Decoder: relu(x@W1+b1)@W2+b2 (reads xA, writes dedicated red) ---
    {
      int ctd = w & 3, rbase = (w >> 2) * 2;
      int dcol = ctd * 16 + l15;
      s16x8 bd0 = ldw(176 + ctd * 4), bd1 = ldw(176 + ctd * 4 + 1);
      s16x8 bd2 = ldw(176 + ctd * 4 + 2), bd3 = ldw(176 + ctd * 4 + 3);
      float d1bv = d1b[dcol], w2v = d2w[dcol];
#pragma unroll
      for (int q = 0; q < 2; ++q) {
        int rg = rbase + q;
        s16x8 xa = ldF(xA, rg * 4), xb = ldF(xA, rg * 4 + 1);
        s16x8 xc = ldF(xA, rg * 4 + 2), xd = ldF(xA, rg * 4 + 3);
        f32x4 hh = {0.f, 0.f, 0.f, 0.f};
        hh = MFMA16(xa, bd0, hh); hh = MFMA16(xb, bd1, hh);
        hh = MFMA16(xc, bd2, hh); hh = MFMA16(xd, bd3, hh);
#pragma unroll
        for (int rr = 0; rr < 4; ++rr) {
          float h = fmaxf(hh[rr] + d1bv, 0.f) * w2v;
          h += __shfl_xor(h, 1);
          h += __shfl_xor(h, 2);
          h += __shfl_xor(h, 4);
          h += __shfl_xor(h, 8);
          if (l15 == 0) red[(rg * 16 + g16 * 4 + rr) * 4 + ctd] = h;
        }
      }
    }
    __syncthreads();
    if (tid < 64) {
      int grow = row0 + tid;
      if (grow < n)
        out[grow] = red[tid * 4 + 0] + red[tid * 4 + 1] + red[tid * 4 + 2] +
                    red[tid * 4 + 3] + d2b[0];
    }
    // no trailing barrier: next stage writes featA/cfA only; red is written
    // again only after two barriers in the next iteration.
  }
}

extern "C" void kernel_launch(void* const* d_in, const int* in_sizes, int n_in,
                              void* d_out, int out_size, void* d_ws, size_t ws_size,
                              hipStream_t stream) {
  int n = in_sizes[0];
  short* pw = (short*)d_ws;   // needs 192 KiB
  pack_w<<<192, 512, 0, stream>>>(
      (const float*)d_in[12],  // film0_fcW
      (const float*)d_in[14],  // filmh_fcW
      (const float*)d_in[16],  // gammaW
      (const float*)d_in[18],  // betaW
      (const float*)d_in[20],  // decW1
      pw);
  int ntiles = (n + 63) / 64;
  int nb = ntiles < NBLK ? ntiles : NBLK;
  ngc_main<<<nb, 512, 0, stream>>>(
      (const float*)d_in[0],   // coords
      (const float*)d_in[1],   // angles
      (const float*)d_in[2],   // rho
      (const float*)d_in[3],   // rho_n
      (const float*)d_in[4],   // curve_feats
      (const float*)d_in[5],   // type_sample
      (const float*)d_in[6],   // gt0
      (const float*)d_in[7],   // gr0   (dict order: per level gt, gr)
      (const float*)d_in[8],   // gt1
      (const float*)d_in[9],   // gr1
      (const float*)d_in[10],  // gt2
      (const float*)d_in[11],  // gr2
      (const float*)d_in[13],  // film0_fcb
      (const float*)d_in[15],  // filmh_fcb
      (const float*)d_in[17],  // gammab
      (const float*)d_in[19],  // betab
      (const float*)d_in[21],  // decb1
      (const float*)d_in[22],  // decW2
      (const float*)d_in[23],  // decb2
      pw, (float*)d_out, n, ntiles);
}

// Round 10
// 284.484 us; speedup vs baseline: 1.2843x; 1.2843x over previous
//
#include <hip/hip_runtime.h>
#include <stdint.h>

typedef short s16x8 __attribute__((ext_vector_type(8)));
typedef float f32x4 __attribute__((ext_vector_type(4)));
typedef uint32_t u32x4 __attribute__((ext_vector_type(4)));

#define MFMA16(a, b, c) __builtin_amdgcn_mfma_f32_16x16x32_bf16(a, b, c, 0, 0, 0)

__device__ __forceinline__ short f2bf(float f) {
  uint32_t u = __builtin_bit_cast(uint32_t, f);
  u += 0x7FFFu + ((u >> 16) & 1u);   // round-to-nearest-even
  return (short)(u >> 16);
}
// 1-op f32->bf16 via HW packed convert (RNE); low 16 bits = cvt(lo).
__device__ __forceinline__ uint32_t cvtpk(float lo, float hi) {
  uint32_t r;
  asm("v_cvt_pk_bf16_f32 %0, %1, %2" : "=v"(r) : "v"(lo), "v"(hi));
  return r;
}
__device__ __forceinline__ short f2bf1(float f) { return (short)cvtpk(f, f); }

// ---------------------------------------------------------------------------
// Weight pre-pack (R4 version, unchanged): bf16, MFMA B-fragment order.
// k = ks*32 + (lane>>4)*8 + e, n = ct*16 + (lane&15).
//   W0 frags 0..15, GB 16..111, WH 112..175, D1 176..191.  192 KiB in d_ws.
// ---------------------------------------------------------------------------
__global__ void pack_w(const float* __restrict__ w0, const float* __restrict__ wh,
                       const float* __restrict__ gw, const float* __restrict__ bw,
                       const float* __restrict__ d1, short* __restrict__ out) {
  int idx = blockIdx.x * 512 + threadIdx.x;
  if (idx >= 98304) return;
  int f = idx >> 9;
  int r = idx & 511;
  int lane = r >> 3, e = r & 7;
  int kk = ((lane >> 4) << 3) + e;
  int nn = lane & 15;
  float v;
  if (f < 16) {
    int ct = f >> 1, ks = f & 1;
    int k = ks * 32 + kk, n = ct * 16 + nn;
    if (k < 48) v = w0[(1 + k) * 128 + n];
    else if (k == 48) v = w0[n];
    else v = 0.f;
  } else if (f < 112) {
    int f2 = f - 16;
    int ks = f2 & 1, ct = (f2 >> 1) & 7, gb = (f2 >> 4) & 1, l = f2 >> 5;
    int k = ks * 32 + kk, n = ct * 16 + nn;
    const float* Wp = gb ? bw : gw;
    v = Wp[(l * 64 + k) * 128 + n];
  } else if (f < 176) {
    int f2 = f - 112;
    int ks = f2 & 3, ct = (f2 >> 2) & 7, i = f2 >> 5;
    int k = ks * 32 + kk, n = ct * 16 + nn;
    v = wh[(i * 128 + k) * 128 + n];
  } else {
    int f2 = f - 176;
    int ks = f2 & 3, ct = f2 >> 2;
    int k = ks * 32 + kk, n = ct * 16 + nn;
    v = d1[k * 64 + n];
  }
  out[idx] = f2bf(v);
}

// ---------------------------------------------------------------------------
// R10 producer: per-point bilinear gathers -> feat tiles in d_ws, already in
// MFMA A-frag layout (8 frags x 1KB per 64-row tile, 8192 B/tile).
// 512 threads per tile: tid<384 = (row, grid) gather; wave 6 = rho col48;
// wave 7 = zero cols 49..63.  No LDS, no barriers -> pure TLP latency engine.
// ---------------------------------------------------------------------------
__global__ __launch_bounds__(512) void ngc_gather(
    const float* __restrict__ coords, const float* __restrict__ angles,
    const float* __restrict__ rho, const float* __restrict__ rho_n,
    const float* __restrict__ gt0, const float* __restrict__ gr0,
    const float* __restrict__ gt1, const float* __restrict__ gr1,
    const float* __restrict__ gt2, const float* __restrict__ gr2,
    short* __restrict__ stage, int n, int t0) {
  const int tid = threadIdx.x;
  const int row0 = (t0 + blockIdx.x) * 64;
  char* st = (char*)(stage + (size_t)blockIdx.x * 4096);  // 8192 B per tile

  if (tid < 384) {
    int r = tid & 63, g = tid >> 6;           // g wave-uniform (waves 0..5)
    int gr_ = row0 + r; gr_ = gr_ < n ? gr_ : n - 1;
    float vv = coords[gr_];
    float u = (g < 3) ? angles[gr_] : rho_n[gr_];
    int lvl = (g < 3) ? g : g - 3;
    const float* G = (g == 0) ? gt0 : (g == 1) ? gt1 : (g == 2) ? gt2
                   : (g == 3) ? gr0 : (g == 4) ? gr1 : gr2;
    int Wg = 128 << lvl;
    float x = u * (float)(Wg - 1), y = vv * (float)(Wg - 1);
    int ix = (int)x; ix = ix < 0 ? 0 : (ix > Wg - 2 ? Wg - 2 : ix);
    int iy = (int)y; iy = iy < 0 ? 0 : (iy > Wg - 2 ? Wg - 2 : iy);
    float wx = x - (float)ix, wy = y - (float)iy;
    const float4* p0 = (const float4*)(G + (size_t)(iy * Wg + ix) * 8);
    const float4* p1 = (const float4*)(G + (size_t)((iy + 1) * Wg + ix) * 8);
    float4 c00a = p0[0], c00b = p0[1], c01a = p0[2], c01b = p0[3];
    float4 c10a = p1[0], c10b = p1[1], c11a = p1[2], c11b = p1[3];
    float w00 = (1.f - wx) * (1.f - wy), w01 = wx * (1.f - wy);
    float w10 = (1.f - wx) * wy, w11 = wx * wy;
    float e0 = c00a.x * w00 + c01a.x * w01 + c10a.x * w10 + c11a.x * w11;
    float e1 = c00a.y * w00 + c01a.y * w01 + c10a.y * w10 + c11a.y * w11;
    float e2 = c00a.z * w00 + c01a.z * w01 + c10a.z * w10 + c11a.z * w11;
    float e3 = c00a.w * w00 + c01a.w * w01 + c10a.w * w10 + c11a.w * w11;
    float e4 = c00b.x * w00 + c01b.x * w01 + c10b.x * w10 + c11b.x * w11;
    float e5 = c00b.y * w00 + c01b.y * w01 + c10b.y * w10 + c11b.y * w11;
    float e6 = c00b.z * w00 + c01b.z * w01 + c10b.z * w10 + c11b.z * w11;
    float e7 = c00b.w * w00 + c01b.w * w01 + c10b.w * w10 + c11b.w * w11;
    u32x4 o = { cvtpk(e0, e1), cvtpk(e2, e3), cvtpk(e4, e5), cvtpk(e6, e7) };
    int dst16 = ((r >> 4) * 2 + (g >> 2)) * 64 + (g & 3) * 16 + (r & 15);
    *(u32x4*)(st + dst16 * 16) = o;
  } else if (tid < 448) {                     // wave 6: rho -> feat col 48
    int r = tid - 384;
    int gr_ = row0 + r; gr_ = gr_ < n ? gr_ : n - 1;
    s16x8 a = { f2bf1(rho[gr_]), 0, 0, 0, 0, 0, 0, 0 };
    int base = ((r >> 4) * 2 + 1) * 64;
    *(s16x8*)(st + (base + 32 + (r & 15)) * 16) = a;
  } else {                                    // wave 7: zeros cols 49..63
    int r = tid - 448;
    s16x8 z = { 0, 0, 0, 0, 0, 0, 0, 0 };
    int base = ((r >> 4) * 2 + 1) * 64;
    *(s16x8*)(st + (base + 48 + (r & 15)) * 16) = z;
  }
}

// ---------------------------------------------------------------------------
// R10 consumer: R4's proven barrier structure, stage phase reduced to a cf
// convert.  feat A-frags are read DIRECTLY from d_ws as coalesced 16B/lane
// global loads (16 KB/tile, L1-resident across the block's 8 waves).
// 512 threads, 64 rows, wave w owns col-tile ct=w; xr f32 register residual;
// in-place xA with read->bar->write->bar; dedicated red.  LDS 25 KiB.
// ---------------------------------------------------------------------------
__global__ __launch_bounds__(512) void ngc_gemm(
    const float* __restrict__ cf, const float* __restrict__ ts,
    const float* __restrict__ f0b, const float* __restrict__ fhb,
    const float* __restrict__ gab, const float* __restrict__ beb,
    const float* __restrict__ d1b, const float* __restrict__ d2w,
    const float* __restrict__ d2b, const short* __restrict__ pw,
    const short* __restrict__ stage, float* __restrict__ out, int n, int t0) {
  __shared__ __align__(16) char smem[25 * 1024];
  char* cfA = smem;                 // 8 KiB: frag = rg*2+ks (ks<2)
  char* xA  = smem + 8 * 1024;      // 16 KiB: frag = rg*4+ks (ks<4)
  float* red = (float*)(smem + 24 * 1024);  // 1 KiB, dedicated

  const int tid = threadIdx.x;
  const int lane = tid & 63;
  const int w = tid >> 6;           // wave id == col-tile ct, 0..7
  const int g16 = lane >> 4;
  const int l15 = lane & 15;
  const int row0 = (t0 + blockIdx.x) * 64;
  const int col = w * 16 + l15;
  const int cbase = col >> 5;
  const int cslot = ((col >> 3) & 3) * 16;
  const int ce = (col & 7) * 2;

  // ---- ts prefetch (16 scalar f32, in flight during cf stage) ------------
  float tsr[4][4];
#pragma unroll
  for (int rg = 0; rg < 4; ++rg)
#pragma unroll
    for (int rr = 0; rr < 4; ++rr) {
      int grow = row0 + rg * 16 + g16 * 4 + rr; grow = grow < n ? grow : n - 1;
      tsr[rg][rr] = ts[(size_t)grow * 128 + col];
    }

  // ---- cf stage: f32 -> bf16 frag-linear LDS (one op/thread) -------------
  {
    int cb = tid & 7, r = tid >> 3;
    int gr_ = row0 + r; gr_ = gr_ < n ? gr_ : n - 1;
    const float4* cp = (const float4*)(cf + (size_t)gr_ * 64 + cb * 8);
    float4 v0 = cp[0], v1 = cp[1];
    u32x4 s = { cvtpk(v0.x, v0.y), cvtpk(v0.z, v0.w),
                cvtpk(v1.x, v1.y), cvtpk(v1.z, v1.w) };
    int dst16 = ((r >> 4) * 2 + (cb >> 2)) * 64 + (cb & 3) * 16 + (r & 15);
    *(u32x4*)(cfA + dst16 * 16) = s;
  }
  __syncthreads();

  const s16x8* fB = (const s16x8*)stage + (size_t)blockIdx.x * 512;
  auto ldfeat = [&](int frag) -> s16x8 { return fB[frag * 64 + lane]; };
  auto ldF = [&](const char* b, int frag) -> s16x8 {
    return *(const s16x8*)(b + (frag * 64 + lane) * 16);
  };
  auto ldw = [&](int frag) -> s16x8 { return ((const s16x8*)pw)[frag * 64 + lane]; };

  float xr[4][4];

  // ---- Layer 0: xr = silu(g0*(feat@W0+b0)+be0) + ts; xA = bf16(xr) -------
  {
    s16x8 bw0 = ldw(w * 2), bw1 = ldw(w * 2 + 1);
    s16x8 bg0 = ldw(16 + w * 2), bg1 = ldw(16 + w * 2 + 1);
    s16x8 bb0 = ldw(32 + w * 2), bb1 = ldw(32 + w * 2 + 1);
    float f0bv = f0b[col], gabv = gab[col], bebv = beb[col];
#pragma unroll
    for (int rg = 0; rg < 4; ++rg) {
      s16x8 a0 = ldfeat(rg * 2), a1 = ldfeat(rg * 2 + 1);
      s16x8 c0 = ldF(cfA, rg * 2), c1 = ldF(cfA, rg * 2 + 1);
      f32x4 t = {0.f, 0.f, 0.f, 0.f};
      t = MFMA16(a0, bw0, t); t = MFMA16(a1, bw1, t);
      f32x4 ga = {0.f, 0.f, 0.f, 0.f};
      ga = MFMA16(c0, bg0, ga); ga = MFMA16(c1, bg1, ga);
      f32x4 be = {0.f, 0.f, 0.f, 0.f};
      be = MFMA16(c0, bb0, be); be = MFMA16(c1, bb1, be);
      char* xbase = xA + (rg * 4 + cbase) * 1024 + ce;
#pragma unroll
      for (int rr = 0; rr < 4; ++rr) {
        float z = (ga[rr] + gabv) * (t[rr] + f0bv) + (be[rr] + bebv);
        float sl = z * __builtin_amdgcn_rcpf(1.f + __expf(-z));
        xr[rg][rr] = sl + tsr[rg][rr];
        *(short*)(xbase + (cslot + g16 * 4 + rr) * 16) = f2bf1(xr[rg][rr]);
      }
    }
  }
  __syncthreads();

  // ---- Residual FiLM blocks: read xA -> bar -> write xA -> bar -----------
#pragma unroll
  for (int i = 0; i < 2; ++i) {
    s16x8 bh0 = ldw(112 + i * 32 + w * 4);
    s16x8 bh1 = ldw(112 + i * 32 + w * 4 + 1);
    s16x8 bh2 = ldw(112 + i * 32 + w * 4 + 2);
    s16x8 bh3 = ldw(112 + i * 32 + w * 4 + 3);
    s16x8 bg0 = ldw(16 + (i + 1) * 32 + w * 2);
    s16x8 bg1 = ldw(16 + (i + 1) * 32 + w * 2 + 1);
    s16x8 bb0 = ldw(16 + (i + 1) * 32 + 16 + w * 2);
    s16x8 bb1 = ldw(16 + (i + 1) * 32 + 16 + w * 2 + 1);
    float fhbv = fhb[i * 128 + col];
    float gabv = gab[(i + 1) * 128 + col];
    float bebv = beb[(i + 1) * 128 + col];
    f32x4 zs[4];
#pragma unroll
    for (int rg = 0; rg < 4; ++rg) {
      s16x8 xa = ldF(xA, rg * 4), xb = ldF(xA, rg * 4 + 1);
      s16x8 xc = ldF(xA, rg * 4 + 2), xd = ldF(xA, rg * 4 + 3);
      s16x8 c0 = ldF(cfA, rg * 2), c1 = ldF(cfA, rg * 2 + 1);
      f32x4 t = {0.f, 0.f, 0.f, 0.f};
      t = MFMA16(xa, bh0, t); t = MFMA16(xb, bh1, t);
      t = MFMA16(xc, bh2, t); t = MFMA16(xd, bh3, t);
      f32x4 ga = {0.f, 0.f, 0.f, 0.f};
      ga = MFMA16(c0, bg0, ga); ga = MFMA16(c1, bg1, ga);
      f32x4 be = {0.f, 0.f, 0.f, 0.f};
      be = MFMA16(c0, bb0, be); be = MFMA16(c1, bb1, be);
      f32x4 z;
#pragma unroll
      for (int rr = 0; rr < 4; ++rr) {
        float zz = (ga[rr] + gabv) * (t[rr] + fhbv) + (be[rr] + bebv);
        z[rr] = zz * __builtin_amdgcn_rcpf(1.f + __expf(-zz));
      }
      zs[rg] = z;
    }
    __syncthreads();   // all waves' MFMA reads of xA complete
#pragma unroll
    for (int rg = 0; rg < 4; ++rg) {
      char* xbase = xA + (rg * 4 + cbase) * 1024 + ce;
#pragma unroll
      for (int rr = 0; rr < 4; ++rr) {
        xr[rg][rr] += zs[rg][rr];
        *(short*)(xbase + (cslot + g16 * 4 + rr) * 16) = f2bf1(xr[rg][rr]);
      }
    }
    __syncthreads();   // in-place writes complete
  }

  // ---- Decoder: relu(x@W1+b1)@W2+b2 (reads xA, writes dedicated red) -----
  {
    int ctd = w & 3, rbase = (w >> 2) * 2;
    int dcol = ctd * 16 + l15;
    s16x8 bd0 = ldw(176 + ctd * 4), bd1 = ldw(176 + ctd * 4 + 1);
    s16x8 bd2 = ldw(176 + ctd * 4 + 2), bd3 = ldw(176 + ctd * 4 + 3);
    float d1bv = d1b[dcol], w2v = d2w[dcol];
#pragma unroll
    for (int q = 0; q < 2; ++q) {
      int rg = rbase + q;
      s16x8 xa = ldF(xA, rg * 4), xb = ldF(xA, rg * 4 + 1);
      s16x8 xc = ldF(xA, rg * 4 + 2), xd = ldF(xA, rg * 4 + 3);
      f32x4 hh = {0.f, 0.f, 0.f, 0.f};
      hh = MFMA16(xa, bd0, hh); hh = MFMA16(xb, bd1, hh);
      hh = MFMA16(xc, bd2, hh); hh = MFMA16(xd, bd3, hh);
#pragma unroll
      for (int rr = 0; rr < 4; ++rr) {
        float h = fmaxf(hh[rr] + d1bv, 0.f) * w2v;
        h += __shfl_xor(h, 1);
        h += __shfl_xor(h, 2);
        h += __shfl_xor(h, 4);
        h += __shfl_xor(h, 8);
        if (l15 == 0) red[(rg * 16 + g16 * 4 + rr) * 4 + ctd] = h;
      }
    }
  }
  __syncthreads();
  if (tid < 64) {
    int grow = row0 + tid;
    if (grow < n)
      out[grow] = red[tid * 4 + 0] + red[tid * 4 + 1] + red[tid * 4 + 2] +
                  red[tid * 4 + 3] + d2b[0];
  }
}

extern "C" void kernel_launch(void* const* d_in, const int* in_sizes, int n_in,
                              void* d_out, int out_size, void* d_ws, size_t ws_size,
                              hipStream_t stream) {
  int n = in_sizes[0];
  short* pw = (short*)d_ws;                        // 192 KiB
  const size_t stage_off = 256 * 1024;             // pw + pad
  short* stage = (short*)((char*)d_ws + stage_off);
  int ntiles = (n + 63) / 64;
  long long avail = (long long)ws_size - (long long)stage_off;
  int chunk = (int)(avail > 8192 ? avail / 8192 : 1);
  if (chunk > ntiles) chunk = ntiles;
  if (chunk < 1) chunk = 1;

  pack_w<<<192, 512, 0, stream>>>(
      (const float*)d_in[12],  // film0_fcW
      (const float*)d_in[14],  // filmh_fcW
      (const float*)d_in[16],  // gammaW
      (const float*)d_in[18],  // betaW
      (const float*)d_in[20],  // decW1
      pw);

  for (int t0 = 0; t0 < ntiles; t0 += chunk) {
    int nb = ntiles - t0 < chunk ? ntiles - t0 : chunk;
    ngc_gather<<<nb, 512, 0, stream>>>(
        (const float*)d_in[0],   // coords
        (const float*)d_in[1],   // angles
        (const float*)d_in[2],   // rho
        (const float*)d_in[3],   // rho_n
        (const float*)d_in[6],   // gt0
        (const float*)d_in[7],   // gr0
        (const float*)d_in[8],   // gt1
        (const float*)d_in[9],   // gr1
        (const float*)d_in[10],  // gt2
        (const float*)d_in[11],  // gr2
        stage, n, t0);
    ngc_gemm<<<nb, 512, 0, stream>>>(
        (const float*)d_in[4],   // curve_feats
        (const float*)d_in[5],   // type_sample
        (const float*)d_in[13],  // film0_fcb
        (const float*)d_in[15],  // filmh_fcb
        (const float*)d_in[17],  // gammab
        (const float*)d_in[19],  // betab
        (const float*)d_in[21],  // decb1
        (const float*)d_in[22],  // decW2
        (const float*)d_in[23],  // decb2
        pw, stage, (float*)d_out, n, t0);
  }
}

// Round 11
// 271.465 us; speedup vs baseline: 1.3459x; 1.0480x over previous
//
#include <hip/hip_runtime.h>
#include <stdint.h>

typedef short s16x8 __attribute__((ext_vector_type(8)));
typedef float f32x4 __attribute__((ext_vector_type(4)));
typedef uint32_t u32x4 __attribute__((ext_vector_type(4)));

#define MFMA16(a, b, c) __builtin_amdgcn_mfma_f32_16x16x32_bf16(a, b, c, 0, 0, 0)

__device__ __forceinline__ short f2bf(float f) {
  uint32_t u = __builtin_bit_cast(uint32_t, f);
  u += 0x7FFFu + ((u >> 16) & 1u);   // round-to-nearest-even
  return (short)(u >> 16);
}
// 1-op f32->bf16 via HW packed convert (RNE); low 16 bits = cvt(lo).
__device__ __forceinline__ uint32_t cvtpk(float lo, float hi) {
  uint32_t r;
  asm("v_cvt_pk_bf16_f32 %0, %1, %2" : "=v"(r) : "v"(lo), "v"(hi));
  return r;
}
__device__ __forceinline__ short f2bf1(float f) { return (short)cvtpk(f, f); }

// ---------------------------------------------------------------------------
// Weight pre-pack: bf16 MFMA fragment order (idx16 = lane&15,
// k = ks*32 + (lane>>4)*8 + e).  W0 frags 0..15, GB 16..111, WH 112..175,
// D1 176..191 (192 KiB).  NEW: decoder bias pack at dpk (f32):
// dpk[ct*256 + lane*4 + rr] = d1b[n], dpk[1024 + ...] = d2w[n],
// n = ct*16 + (lane>>4)*4 + rr  (matches D-layout of the swapped decoder).
// ---------------------------------------------------------------------------
__global__ void pack_w(const float* __restrict__ w0, const float* __restrict__ wh,
                       const float* __restrict__ gw, const float* __restrict__ bw,
                       const float* __restrict__ d1, const float* __restrict__ d1bp,
                       const float* __restrict__ d2wp, short* __restrict__ out,
                       float* __restrict__ dpk) {
  int idx = blockIdx.x * 512 + threadIdx.x;
  if (idx < 98304) {
    int f = idx >> 9;
    int r = idx & 511;
    int lane = r >> 3, e = r & 7;
    int kk = ((lane >> 4) << 3) + e;
    int nn = lane & 15;
    float v;
    if (f < 16) {
      int ct = f >> 1, ks = f & 1;
      int k = ks * 32 + kk, n = ct * 16 + nn;
      if (k < 48) v = w0[(1 + k) * 128 + n];
      else if (k == 48) v = w0[n];
      else v = 0.f;
    } else if (f < 112) {
      int f2 = f - 16;
      int ks = f2 & 1, ct = (f2 >> 1) & 7, gb = (f2 >> 4) & 1, l = f2 >> 5;
      int k = ks * 32 + kk, n = ct * 16 + nn;
      const float* Wp = gb ? bw : gw;
      v = Wp[(l * 64 + k) * 128 + n];
    } else if (f < 176) {
      int f2 = f - 112;
      int ks = f2 & 3, ct = (f2 >> 2) & 7, i = f2 >> 5;
      int k = ks * 32 + kk, n = ct * 16 + nn;
      v = wh[(i * 128 + k) * 128 + n];
    } else {
      int f2 = f - 176;
      int ks = f2 & 3, ct = f2 >> 2;
      int k = ks * 32 + kk, n = ct * 16 + nn;
      v = d1[k * 64 + n];
    }
    out[idx] = f2bf(v);
  } else if (idx < 100352) {
    int j = idx - 98304;             // 0..2047
    int which = j >> 10;
    int k = j & 1023;
    int ct = k >> 8, lane = (k >> 2) & 63, rr = k & 3;
    int n2 = ct * 16 + ((lane >> 4) << 2) + rr;
    dpk[j] = which ? d2wp[n2] : d1bp[n2];
  }
}

// ---------------------------------------------------------------------------
// Producer (unchanged from R10): bilinear gathers -> feat tiles in d_ws in
// MFMA A-frag layout (8 frags x 1KB per 64-row tile).  No LDS, no barriers.
// ---------------------------------------------------------------------------
__global__ __launch_bounds__(512) void ngc_gather(
    const float* __restrict__ coords, const float* __restrict__ angles,
    const float* __restrict__ rho, const float* __restrict__ rho_n,
    const float* __restrict__ gt0, const float* __restrict__ gr0,
    const float* __restrict__ gt1, const float* __restrict__ gr1,
    const float* __restrict__ gt2, const float* __restrict__ gr2,
    short* __restrict__ stage, int n, int t0) {
  const int tid = threadIdx.x;
  const int row0 = (t0 + blockIdx.x) * 64;
  char* st = (char*)(stage + (size_t)blockIdx.x * 4096);

  if (tid < 384) {
    int r = tid & 63, g = tid >> 6;
    int gr_ = row0 + r; gr_ = gr_ < n ? gr_ : n - 1;
    float vv = coords[gr_];
    float u = (g < 3) ? angles[gr_] : rho_n[gr_];
    int lvl = (g < 3) ? g : g - 3;
    const float* G = (g == 0) ? gt0 : (g == 1) ? gt1 : (g == 2) ? gt2
                   : (g == 3) ? gr0 : (g == 4) ? gr1 : gr2;
    int Wg = 128 << lvl;
    float x = u * (float)(Wg - 1), y = vv * (float)(Wg - 1);
    int ix = (int)x; ix = ix < 0 ? 0 : (ix > Wg - 2 ? Wg - 2 : ix);
    int iy = (int)y; iy = iy < 0 ? 0 : (iy > Wg - 2 ? Wg - 2 : iy);
    float wx = x - (float)ix, wy = y - (float)iy;
    const float4* p0 = (const float4*)(G + (size_t)(iy * Wg + ix) * 8);
    const float4* p1 = (const float4*)(G + (size_t)((iy + 1) * Wg + ix) * 8);
    float4 c00a = p0[0], c00b = p0[1], c01a = p0[2], c01b = p0[3];
    float4 c10a = p1[0], c10b = p1[1], c11a = p1[2], c11b = p1[3];
    float w00 = (1.f - wx) * (1.f - wy), w01 = wx * (1.f - wy);
    float w10 = (1.f - wx) * wy, w11 = wx * wy;
    float e0 = c00a.x * w00 + c01a.x * w01 + c10a.x * w10 + c11a.x * w11;
    float e1 = c00a.y * w00 + c01a.y * w01 + c10a.y * w10 + c11a.y * w11;
    float e2 = c00a.z * w00 + c01a.z * w01 + c10a.z * w10 + c11a.z * w11;
    float e3 = c00a.w * w00 + c01a.w * w01 + c10a.w * w10 + c11a.w * w11;
    float e4 = c00b.x * w00 + c01b.x * w01 + c10b.x * w10 + c11b.x * w11;
    float e5 = c00b.y * w00 + c01b.y * w01 + c10b.y * w10 + c11b.y * w11;
    float e6 = c00b.z * w00 + c01b.z * w01 + c10b.z * w10 + c11b.z * w11;
    float e7 = c00b.w * w00 + c01b.w * w01 + c10b.w * w10 + c11b.w * w11;
    u32x4 o = { cvtpk(e0, e1), cvtpk(e2, e3), cvtpk(e4, e5), cvtpk(e6, e7) };
    int dst16 = ((r >> 4) * 2 + (g >> 2)) * 64 + (g & 3) * 16 + (r & 15);
    *(u32x4*)(st + dst16 * 16) = o;
  } else if (tid < 448) {
    int r = tid - 384;
    int gr_ = row0 + r; gr_ = gr_ < n ? gr_ : n - 1;
    s16x8 a = { f2bf1(rho[gr_]), 0, 0, 0, 0, 0, 0, 0 };
    int base = ((r >> 4) * 2 + 1) * 64;
    *(s16x8*)(st + (base + 32 + (r & 15)) * 16) = a;
  } else {
    int r = tid - 448;
    s16x8 z = { 0, 0, 0, 0, 0, 0, 0, 0 };
    int base = ((r >> 4) * 2 + 1) * 64;
    *(s16x8*)(st + (base + 48 + (r & 15)) * 16) = z;
  }
}

// ---------------------------------------------------------------------------
// R11 consumer: 4 barriers/tile.
//   b1 after cf stage; L0 writes x0; b2; R1 reads x0 writes x1; b3;
//   R2 reads x1 writes x0; b4; decoder (waves 0-3, swapped operands,
//   in-register n-reduction + 2 shfl, direct out store, no red/no barrier).
// LDS 40KB = cfA 8K + x0 16K + x1 16K -> 4 blocks/CU.
// ---------------------------------------------------------------------------
__global__ __launch_bounds__(512) void ngc_gemm(
    const float* __restrict__ cf, const float* __restrict__ ts,
    const float* __restrict__ f0b, const float* __restrict__ fhb,
    const float* __restrict__ gab, const float* __restrict__ beb,
    const float* __restrict__ d2b, const short* __restrict__ pw,
    const float* __restrict__ dpk, const short* __restrict__ stage,
    float* __restrict__ out, int n, int t0) {
  __shared__ __align__(16) char smem[40 * 1024];
  char* cfA = smem;                 // 8 KiB: frag = rg*2+ks (ks<2)
  char* x0  = smem + 8 * 1024;      // 16 KiB: frag = rg*4+ks (ks<4)
  char* x1  = smem + 24 * 1024;     // 16 KiB

  const int tid = threadIdx.x;
  const int lane = tid & 63;
  const int w = tid >> 6;           // wave id == col-tile ct, 0..7
  const int g16 = lane >> 4;
  const int l15 = lane & 15;
  const int row0 = (t0 + blockIdx.x) * 64;
  const int col = w * 16 + l15;
  const int cbase = col >> 5;
  const int cslot = ((col >> 3) & 3) * 16;
  const int ce = (col & 7) * 2;

  const float d2b0 = d2b[0];

  // ---- ts prefetch (16 scalar f32, in flight during cf stage) ------------
  float tsr[4][4];
#pragma unroll
  for (int rg = 0; rg < 4; ++rg)
#pragma unroll
    for (int rr = 0; rr < 4; ++rr) {
      int grow = row0 + rg * 16 + g16 * 4 + rr; grow = grow < n ? grow : n - 1;
      tsr[rg][rr] = ts[(size_t)grow * 128 + col];
    }

  // ---- cf stage: f32 -> bf16 frag-linear LDS -----------------------------
  {
    int cb = tid & 7, r = tid >> 3;
    int gr_ = row0 + r; gr_ = gr_ < n ? gr_ : n - 1;
    const float4* cp = (const float4*)(cf + (size_t)gr_ * 64 + cb * 8);
    float4 v0 = cp[0], v1 = cp[1];
    u32x4 s = { cvtpk(v0.x, v0.y), cvtpk(v0.z, v0.w),
                cvtpk(v1.x, v1.y), cvtpk(v1.z, v1.w) };
    int dst16 = ((r >> 4) * 2 + (cb >> 2)) * 64 + (cb & 3) * 16 + (r & 15);
    *(u32x4*)(cfA + dst16 * 16) = s;
  }
  __syncthreads();                  // b1

  const s16x8* fB = (const s16x8*)stage + (size_t)blockIdx.x * 512;
  auto ldfeat = [&](int frag) -> s16x8 { return fB[frag * 64 + lane]; };
  auto ldF = [&](const char* b, int frag) -> s16x8 {
    return *(const s16x8*)(b + (frag * 64 + lane) * 16);
  };
  auto ldw = [&](int frag) -> s16x8 { return ((const s16x8*)pw)[frag * 64 + lane]; };

  float xr[4][4];

  // ---- Layer 0: xr = silu(g0*(feat@W0+b0)+be0) + ts; x0 = bf16(xr) -------
  {
    s16x8 bw0 = ldw(w * 2), bw1 = ldw(w * 2 + 1);
    s16x8 bg0 = ldw(16 + w * 2), bg1 = ldw(16 + w * 2 + 1);
    s16x8 bb0 = ldw(32 + w * 2), bb1 = ldw(32 + w * 2 + 1);
    float f0bv = f0b[col], gabv = gab[col], bebv = beb[col];
#pragma unroll
    for (int rg = 0; rg < 4; ++rg) {
      s16x8 a0 = ldfeat(rg * 2), a1 = ldfeat(rg * 2 + 1);
      s16x8 c0 = ldF(cfA, rg * 2), c1 = ldF(cfA, rg * 2 + 1);
      f32x4 t = {0.f, 0.f, 0.f, 0.f};
      t = MFMA16(a0, bw0, t); t = MFMA16(a1, bw1, t);
      f32x4 ga = {0.f, 0.f, 0.f, 0.f};
      ga = MFMA16(c0, bg0, ga); ga = MFMA16(c1, bg1, ga);
      f32x4 be = {0.f, 0.f, 0.f, 0.f};
      be = MFMA16(c0, bb0, be); be = MFMA16(c1, bb1, be);
      char* xbase = x0 + (rg * 4 + cbase) * 1024 + ce;
#pragma unroll
      for (int rr = 0; rr < 4; ++rr) {
        float z = (ga[rr] + gabv) * (t[rr] + f0bv) + (be[rr] + bebv);
        float sl = z * __builtin_amdgcn_rcpf(1.f + __expf(-z));
        xr[rg][rr] = sl + tsr[rg][rr];
        *(short*)(xbase + (cslot + g16 * 4 + rr) * 16) = f2bf1(xr[rg][rr]);
      }
    }
  }
  __syncthreads();                  // b2

  // ---- Residual FiLM blocks: read src buf -> write dst buf -> barrier ----
#pragma unroll
  for (int i = 0; i < 2; ++i) {
    const char* xsrc = i ? x1 : x0;
    char* xdst = i ? x0 : x1;
    s16x8 bh0 = ldw(112 + i * 32 + w * 4);
    s16x8 bh1 = ldw(112 + i * 32 + w * 4 + 1);
    s16x8 bh2 = ldw(112 + i * 32 + w * 4 + 2);
    s16x8 bh3 = ldw(112 + i * 32 + w * 4 + 3);
    s16x8 bg0 = ldw(16 + (i + 1) * 32 + w * 2);
    s16x8 bg1 = ldw(16 + (i + 1) * 32 + w * 2 + 1);
    s16x8 bb0 = ldw(16 + (i + 1) * 32 + 16 + w * 2);
    s16x8 bb1 = ldw(16 + (i + 1) * 32 + 16 + w * 2 + 1);
    float fhbv = fhb[i * 128 + col];
    float gabv = gab[(i + 1) * 128 + col];
    float bebv = beb[(i + 1) * 128 + col];
#pragma unroll
    for (int rg = 0; rg < 4; ++rg) {
      s16x8 xa = ldF(xsrc, rg * 4), xb = ldF(xsrc, rg * 4 + 1);
      s16x8 xc = ldF(xsrc, rg * 4 + 2), xd = ldF(xsrc, rg * 4 + 3);
      s16x8 c0 = ldF(cfA, rg * 2), c1 = ldF(cfA, rg * 2 + 1);
      f32x4 t = {0.f, 0.f, 0.f, 0.f};
      t = MFMA16(xa, bh0, t); t = MFMA16(xb, bh1, t);
      t = MFMA16(xc, bh2, t); t = MFMA16(xd, bh3, t);
      f32x4 ga = {0.f, 0.f, 0.f, 0.f};
      ga = MFMA16(c0, bg0, ga); ga = MFMA16(c1, bg1, ga);
      f32x4 be = {0.f, 0.f, 0.f, 0.f};
      be = MFMA16(c0, bb0, be); be = MFMA16(c1, bb1, be);
      char* xbase = xdst + (rg * 4 + cbase) * 1024 + ce;
#pragma unroll
      for (int rr = 0; rr < 4; ++rr) {
        float zz = (ga[rr] + gabv) * (t[rr] + fhbv) + (be[rr] + bebv);
        xr[rg][rr] += zz * __builtin_amdgcn_rcpf(1.f + __expf(-zz));
        *(short*)(xbase + (cslot + g16 * 4 + rr) * 16) = f2bf1(xr[rg][rr]);
      }
    }
    __syncthreads();                // b3 (i=0), b4 (i=1)
  }

  // ---- Decoder (waves 0-3): swapped operands, x as B-frag from x0 --------
  // D[n][point]: lane l -> point = l&15, n = ct*16 + (l>>4)*4 + rr.
  if (w < 4) {
    const int rg = w;
    s16x8 xF0 = ldF(x0, rg * 4), xF1 = ldF(x0, rg * 4 + 1);
    s16x8 xF2 = ldF(x0, rg * 4 + 2), xF3 = ldF(x0, rg * 4 + 3);
    float s = 0.f;
#pragma unroll
    for (int ct = 0; ct < 4; ++ct) {
      f32x4 hh = {0.f, 0.f, 0.f, 0.f};
      hh = MFMA16(ldw(176 + ct * 4 + 0), xF0, hh);
      hh = MFMA16(ldw(176 + ct * 4 + 1), xF1, hh);
      hh = MFMA16(ldw(176 + ct * 4 + 2), xF2, hh);
      hh = MFMA16(ldw(176 + ct * 4 + 3), xF3, hh);
      f32x4 db = *(const f32x4*)&dpk[ct * 256 + lane * 4];
      f32x4 wv = *(const f32x4*)&dpk[1024 + ct * 256 + lane * 4];
#pragma unroll
      for (int rr = 0; rr < 4; ++rr)
        s += fmaxf(hh[rr] + db[rr], 0.f) * wv[rr];
    }
    s += __shfl_xor(s, 16);
    s += __shfl_xor(s, 32);
    if (g16 == 0) {
      int grow = row0 + rg * 16 + l15;
      if (grow < n) out[grow] = s + d2b0;
    }
  }
}

extern "C" void kernel_launch(void* const* d_in, const int* in_sizes, int n_in,
                              void* d_out, int out_size, void* d_ws, size_t ws_size,
                              hipStream_t stream) {
  int n = in_sizes[0];
  short* pw = (short*)d_ws;                        // 192 KiB
  float* dpk = (float*)((char*)d_ws + 192 * 1024); // 8 KiB decoder bias pack
  const size_t stage_off = 256 * 1024;
  short* stage = (short*)((char*)d_ws + stage_off);
  int ntiles = (n + 63) / 64;
  long long avail = (long long)ws_size - (long long)stage_off;
  int chunk = (int)(avail > 8192 ? avail / 8192 : 1);
  if (chunk > ntiles) chunk = ntiles;
  if (chunk < 1) chunk = 1;

  pack_w<<<196, 512, 0, stream>>>(
      (const float*)d_in[12],  // film0_fcW
      (const float*)d_in[14],  // filmh_fcW
      (const float*)d_in[16],  // gammaW
      (const float*)d_in[18],  // betaW
      (const float*)d_in[20],  // decW1
      (const float*)d_in[21],  // decb1  (dec pack)
      (const float*)d_in[22],  // decW2  (dec pack)
      pw, dpk);

  for (int t0 = 0; t0 < ntiles; t0 += chunk) {
    int nb = ntiles - t0 < chunk ? ntiles - t0 : chunk;
    ngc_gather<<<nb, 512, 0, stream>>>(
        (const float*)d_in[0],   // coords
        (const float*)d_in[1],   // angles
        (const float*)d_in[2],   // rho
        (const float*)d_in[3],   // rho_n
        (const float*)d_in[6],   // gt0
        (const float*)d_in[7],   // gr0
        (const float*)d_in[8],   // gt1
        (const float*)d_in[9],   // gr1
        (const float*)d_in[10],  // gt2
        (const float*)d_in[11],  // gr2
        stage, n, t0);
    ngc_gemm<<<nb, 512, 0, stream>>>(
        (const float*)d_in[4],   // curve_feats
        (const float*)d_in[5],   // type_sample
        (const float*)d_in[13],  // film0_fcb
        (const float*)d_in[15],  // filmh_fcb
        (const float*)d_in[17],  // gammab
        (const float*)d_in[19],  // betab
        (const float*)d_in[23],  // decb2
        pw, dpk, stage, (float*)d_out, n, t0);
  }
}